// Round 1
// baseline (65.596 us; speedup 1.0000x reference)
//
#include <hip/hip_runtime.h>
#include <hip/hip_bf16.h>

#define B_ROWS 8192
#define D_DIM  128
#define S_CHUNKS 32              // column chunks per row-block
#define COLS_PER_CHUNK (B_ROWS / S_CHUNKS)   // 256 cols = 16 tiles of 16
#define ROWS_PER_WAVE 64

typedef __attribute__((ext_vector_type(8))) __bf16 bf16x8;
typedef __attribute__((ext_vector_type(4))) float  f32x4;

// ---------------- Kernel 1: l2-normalize rows, cast to bf16 ----------------
__global__ void k_norm(const float* __restrict__ z, __hip_bfloat16* __restrict__ zn) {
    int row  = blockIdx.x * 4 + (threadIdx.x >> 6);
    int lane = threadIdx.x & 63;
    const float2 v = reinterpret_cast<const float2*>(z + (size_t)row * D_DIM)[lane];
    float ss = v.x * v.x + v.y * v.y;
    #pragma unroll
    for (int m = 1; m < 64; m <<= 1) ss += __shfl_xor(ss, m);
    float inv = rsqrtf(fmaxf(ss, 1e-12f));
    __hip_bfloat162 o;
    o.x = __float2bfloat16(v.x * inv);
    o.y = __float2bfloat16(v.y * inv);
    reinterpret_cast<__hip_bfloat162*>(zn + (size_t)row * D_DIM)[lane] = o;
}

// ---------------- Kernel 2: similarity + partial exp-sums ----------------
// Each wave: 64 rows (4 strips of 16) x one 256-column chunk.
// s_partial layout: [S_CHUNKS][B_ROWS]  (coalesced for the reduce kernel)
__global__ __launch_bounds__(256) void k_sim(const __bf16* __restrict__ zn,
                                             float* __restrict__ s_partial,
                                             float* __restrict__ pos) {
    const int waveId = blockIdx.x * 4 + (threadIdx.x >> 6);
    const int rb = waveId / S_CHUNKS;      // 0..127
    const int cc = waveId % S_CHUNKS;      // 0..31
    const int lane = threadIdx.x & 63;
    const int l15 = lane & 15;
    const int lg  = lane >> 4;             // 0..3
    const int rowBase = rb * ROWS_PER_WAVE;

    // A fragments: strip t, k-step ks -> contiguous 16B per lane
    bf16x8 a[4][4];
    #pragma unroll
    for (int t = 0; t < 4; ++t)
        #pragma unroll
        for (int ks = 0; ks < 4; ++ks)
            a[t][ks] = *reinterpret_cast<const bf16x8*>(
                zn + (rowBase + t * 16 + l15) * D_DIM + ks * 32 + lg * 8);

    float s[4][4] = {};

    const int colStart = cc * COLS_PER_CHUNK;
    const int colEnd   = colStart + COLS_PER_CHUNK;
    // exp(sim - 2) = exp2(acc * (2*log2e) + (-2*log2e)), sim = 2*acc
    const float C1 = 2.0f * 1.4426950408889634f;
    const float C0 = -2.0f * 1.4426950408889634f;

    for (int colBase = colStart; colBase < colEnd; colBase += 16) {
        bf16x8 b[4];
        #pragma unroll
        for (int ks = 0; ks < 4; ++ks)
            b[ks] = *reinterpret_cast<const bf16x8*>(
                zn + (colBase + l15) * D_DIM + ks * 32 + lg * 8);

        const int col = colBase + l15;
        const bool special = ((unsigned)(colBase - rowBase) < (unsigned)ROWS_PER_WAVE);

        #pragma unroll
        for (int t = 0; t < 4; ++t) {
            f32x4 acc = {0.f, 0.f, 0.f, 0.f};
            #pragma unroll
            for (int ks = 0; ks < 4; ++ks)
                acc = __builtin_amdgcn_mfma_f32_16x16x32_bf16(a[t][ks], b[ks], acc, 0, 0, 0);
            #pragma unroll
            for (int r = 0; r < 4; ++r) {
                float e = exp2f(fmaf(acc[r], C1, C0));
                if (special) {
                    int row = rowBase + t * 16 + lg * 4 + r;
                    if (col == row) e = 0.f;                    // mask self
                    if (col == (row ^ 1)) pos[row] = acc[r] * 2.0f; // partner sim
                }
                s[t][r] += e;
            }
        }
    }

    // reduce across the 16 lanes sharing a row (same lg, varying l15)
    #pragma unroll
    for (int t = 0; t < 4; ++t)
        #pragma unroll
        for (int r = 0; r < 4; ++r) {
            float v = s[t][r];
            v += __shfl_xor(v, 1);
            v += __shfl_xor(v, 2);
            v += __shfl_xor(v, 4);
            v += __shfl_xor(v, 8);
            if (l15 == 0) {
                int row = rowBase + t * 16 + lg * 4 + r;
                s_partial[cc * B_ROWS + row] = v;
            }
        }
}

// ---------------- Kernel 3: per-row loss, per-block partial sums ----------------
__global__ void k_loss_partial(const float* __restrict__ sp, const float* __restrict__ pos,
                               float* __restrict__ part) {
    int i = blockIdx.x * 256 + threadIdx.x;
    float ssum = 0.f;
    #pragma unroll
    for (int c = 0; c < S_CHUNKS; ++c) ssum += sp[c * B_ROWS + i];
    float v = 2.0f + logf(ssum) - pos[i];
    #pragma unroll
    for (int m = 1; m < 64; m <<= 1) v += __shfl_xor(v, m);
    __shared__ float ls[4];
    if ((threadIdx.x & 63) == 0) ls[threadIdx.x >> 6] = v;
    __syncthreads();
    if (threadIdx.x == 0) part[blockIdx.x] = ls[0] + ls[1] + ls[2] + ls[3];
}

// ---------------- Kernel 4: final reduce ----------------
__global__ void k_final(const float* __restrict__ part, float* __restrict__ out) {
    float v = (threadIdx.x < (B_ROWS / 256)) ? part[threadIdx.x] : 0.f;
    #pragma unroll
    for (int m = 1; m < 64; m <<= 1) v += __shfl_xor(v, m);
    if (threadIdx.x == 0) out[0] = v * (1.0f / (float)B_ROWS);
}

extern "C" void kernel_launch(void* const* d_in, const int* in_sizes, int n_in,
                              void* d_out, int out_size, void* d_ws, size_t ws_size,
                              hipStream_t stream) {
    const float* z = (const float*)d_in[0];
    float* out = (float*)d_out;

    char* ws = (char*)d_ws;
    __hip_bfloat16* zn = (__hip_bfloat16*)ws;                       // 2 MB
    float* s_partial = (float*)(ws + (size_t)B_ROWS * D_DIM * 2);   // 1 MB
    float* pos = (float*)((char*)s_partial + (size_t)S_CHUNKS * B_ROWS * 4); // 32 KB
    float* part = (float*)((char*)pos + (size_t)B_ROWS * 4);        // 128 B

    // 1) normalize + bf16 cast: 4 rows per 256-thread block
    k_norm<<<B_ROWS / 4, 256, 0, stream>>>(z, zn);

    // 2) similarity + partial sums: 128 row-blocks x 32 col-chunks, 4 waves/block
    k_sim<<<(128 * S_CHUNKS) / 4, 256, 0, stream>>>((const __bf16*)zn, s_partial, pos);

    // 3) per-row loss -> 32 block partials
    k_loss_partial<<<B_ROWS / 256, 256, 0, stream>>>(s_partial, pos, part);

    // 4) final scalar
    k_final<<<1, 64, 0, stream>>>(part, out);
}